// Round 3
// baseline (51.009 us; speedup 1.0000x reference)
//
#include <hip/hip_runtime.h>

#define BATCH 128
#define TLEN  160000
#define NSEG  200
#define CHUNK 1024                 // samples per block in apply kernel
#define NCHUNK ((TLEN + CHUNK - 1) / CHUNK)   // 157

// Kernel 0: one block per batch row.
//  (a) coalesced load of 200 segment lengths, LDS scan -> exclusive prefix
//  (b) eff/start/end per segment (exact reference float math)
//  (c) bitonic sort (start,end) by start in LDS
//  (d) serial merge (thread 0) into sorted DISJOINT intervals
//  (e) write merged intervals + count to workspace
__global__ void pl_segments(const float* __restrict__ ratio,
                            const int* __restrict__ seg_len_raw,
                            const float* __restrict__ start_u,
                            int* __restrict__ mstart,
                            int* __restrict__ mend,
                            int* __restrict__ mcount) {
    const int b   = blockIdx.x;
    const int tid = threadIdx.x;
    __shared__ int ss[256];   // starts (sort key)
    __shared__ int se[256];   // ends
    __shared__ int sc[256];   // scan buffer
    __shared__ int ms[256];   // merged starts
    __shared__ int me[256];   // merged ends
    __shared__ int mc;

    const int base = b * NSEG;
    int len = (tid < NSEG) ? seg_len_raw[base + tid] : 0;

    // inclusive scan of lengths
    sc[tid] = len;
    __syncthreads();
    #pragma unroll
    for (int off = 1; off < 256; off <<= 1) {
        int t = (tid >= off) ? sc[tid - off] : 0;
        __syncthreads();
        sc[tid] += t;
        __syncthreads();
    }

    // per-segment interval
    if (tid < NSEG) {
        int total = (int)floorf((float)TLEN * ratio[b]);   // matches reference
        int prev  = sc[tid] - len;                          // exclusive prefix
        int rem   = total - prev;
        int eff   = rem < 0 ? 0 : (rem > len ? len : rem);  // clip(total-prev,0,len)
        float u   = start_u[base + tid];
        int start = (int)floorf(u * (float)(TLEN - eff + 1));
        ss[tid] = start;
        se[tid] = start + eff;
    } else {
        ss[tid] = 0x7FFFFFFF;   // pad sorts last
        se[tid] = 0x7FFFFFFF;
    }

    // bitonic sort 256 entries by start (pairs move together)
    for (int k = 2; k <= 256; k <<= 1) {
        for (int j = k >> 1; j > 0; j >>= 1) {
            __syncthreads();
            int ixj = tid ^ j;
            if (ixj > tid) {
                int a = ss[tid], c = ss[ixj];
                bool up = ((tid & k) == 0);
                if ((a > c) == up) {
                    int ea = se[tid], ec = se[ixj];
                    ss[tid] = c;  ss[ixj] = a;
                    se[tid] = ec; se[ixj] = ea;
                }
            }
        }
    }
    __syncthreads();

    // serial merge of the 200 sorted intervals into disjoint runs
    if (tid == 0) {
        int cnt = 0;
        int cs = ss[0], ce = se[0];
        for (int i = 1; i < NSEG; ++i) {
            int s = ss[i], e = se[i];
            if (s <= ce) { ce = (e > ce) ? e : ce; }
            else { ms[cnt] = cs; me[cnt] = ce; ++cnt; cs = s; ce = e; }
        }
        ms[cnt] = cs; me[cnt] = ce; ++cnt;
        mc = cnt;
    }
    __syncthreads();

    int n = mc;
    if (tid < n) {
        mstart[b * 256 + tid] = ms[tid];
        mend  [b * 256 + tid] = me[tid];
    }
    if (tid == 0) mcount[b] = n;
}

// Kernel 1: fused copy+mask. One block per (row, 1024-sample chunk).
// Stages the row's merged intervals in LDS; per-thread binary search for the
// first interval with end > s; fully-covered float4s skip the audio read.
__global__ void pl_apply(const float* __restrict__ audio,
                         const int* __restrict__ mstart,
                         const int* __restrict__ mend,
                         const int* __restrict__ mcount,
                         float* __restrict__ out) {
    const int b    = blockIdx.y;
    const int tid  = threadIdx.x;
    const int c0   = blockIdx.x * CHUNK;
    __shared__ int ls[256];
    __shared__ int le[256];

    const int n = mcount[b];               // uniform -> scalar load
    if (tid < n) {
        ls[tid] = mstart[b * 256 + tid];
        le[tid] = mend  [b * 256 + tid];
    }
    __syncthreads();

    const int s = c0 + tid * 4;
    if (s >= TLEN) return;

    // first interval with end > s (ends strictly increasing)
    int lo = 0, hi = n;
    while (lo < hi) {
        int mid = (lo + hi) >> 1;
        if (le[mid] > s) hi = mid; else lo = mid + 1;
    }

    bool v0 = false, v1 = false, v2 = false, v3 = false;
    for (int i = lo; i < n && ls[i] < s + 4; ++i) {
        int a = ls[i], e = le[i];
        v0 |= (s     >= a) & (s     < e);
        v1 |= (s + 1 >= a) & (s + 1 < e);
        v2 |= (s + 2 >= a) & (s + 2 < e);
        v3 |= (s + 3 >= a) & (s + 3 < e);
    }

    const size_t idx = (size_t)b * TLEN + s;
    float4 v;
    if (v0 & v1 & v2 & v3) {
        v = make_float4(0.f, 0.f, 0.f, 0.f);   // no fetch for covered lanes
    } else {
        v = *(const float4*)(audio + idx);
        if (v0) v.x = 0.f;
        if (v1) v.y = 0.f;
        if (v2) v.z = 0.f;
        if (v3) v.w = 0.f;
    }
    *(float4*)(out + idx) = v;
}

extern "C" void kernel_launch(void* const* d_in, const int* in_sizes, int n_in,
                              void* d_out, int out_size, void* d_ws, size_t ws_size,
                              hipStream_t stream) {
    const float* audio       = (const float*)d_in[0];
    const float* ratio       = (const float*)d_in[1];
    const int*   seg_len_raw = (const int*)d_in[2];
    const float* start_u     = (const float*)d_in[3];
    float* out = (float*)d_out;

    int* mstart = (int*)d_ws;               // [BATCH][256]
    int* mend   = mstart + BATCH * 256;     // [BATCH][256]
    int* mcount = mend   + BATCH * 256;     // [BATCH]

    pl_segments<<<BATCH, 256, 0, stream>>>(ratio, seg_len_raw, start_u,
                                           mstart, mend, mcount);

    dim3 grid(NCHUNK, BATCH);
    pl_apply<<<grid, 256, 0, stream>>>(audio, mstart, mend, mcount, out);
}

// Round 4
// 37.733 us; speedup vs baseline: 1.3519x; 1.3519x over previous
//
#include <hip/hip_runtime.h>

#define BATCH 128
#define TLEN  160000
#define NSEG  200
#define CHUNK 1024
#define NCHUNK ((TLEN + CHUNK - 1) / CHUNK)   // 157
#define WPR   ((TLEN + 31) / 32)              // 5000 mask words per row

// Kernel 0: one block per row. LDS scan of segment lengths -> eff/start/end
// (exact reference float math). Optionally zeroes the row's coverage bitmask.
__global__ void pl_segments(const float* __restrict__ ratio,
                            const int* __restrict__ seg_len_raw,
                            const float* __restrict__ start_u,
                            int* __restrict__ seg_start,
                            int* __restrict__ seg_end,
                            unsigned int* __restrict__ mask) {   // may be null
    const int b   = blockIdx.x;
    const int tid = threadIdx.x;
    __shared__ int sc[256];

    if (mask) {
        unsigned int* row = mask + (size_t)b * WPR;
        for (int w = tid; w < WPR; w += 256) row[w] = 0u;
    }

    const int base = b * NSEG;
    int len = (tid < NSEG) ? seg_len_raw[base + tid] : 0;

    sc[tid] = len;
    __syncthreads();
    #pragma unroll
    for (int off = 1; off < 256; off <<= 1) {
        int t = (tid >= off) ? sc[tid - off] : 0;
        __syncthreads();
        sc[tid] += t;
        __syncthreads();
    }

    if (tid < NSEG) {
        int total = (int)floorf((float)TLEN * ratio[b]);    // matches reference
        int prev  = sc[tid] - len;                          // exclusive prefix
        int rem   = total - prev;
        int eff   = rem < 0 ? 0 : (rem > len ? len : rem);  // clip(total-prev,0,len)
        float u   = start_u[base + tid];
        int start = (int)floorf(u * (float)(TLEN - eff + 1));
        seg_start[base + tid] = start;
        seg_end[base + tid]   = start + eff;
    }
}

// Kernel 1a: one 64-thread block per (b,seg); atomicOr the segment's bit range.
__global__ void pl_paint(const int* __restrict__ seg_start,
                         const int* __restrict__ seg_end,
                         unsigned int* __restrict__ mask) {
    const int idx = blockIdx.x;             // b*NSEG + s
    const int b   = idx / NSEG;
    const int s0  = seg_start[idx];
    const int s1  = seg_end[idx];
    if (s0 >= s1) return;
    unsigned int* row = mask + (size_t)b * WPR;
    const int w0 = s0 >> 5;
    const int w1 = (s1 - 1) >> 5;           // inclusive
    for (int w = w0 + (int)threadIdx.x; w <= w1; w += 64) {
        int lo = s0 - (w << 5); if (lo < 0) lo = 0;
        int hi = s1 - (w << 5); if (hi > 32) hi = 32;
        unsigned int bits = (hi == 32 ? 0xFFFFFFFFu : ((1u << hi) - 1u))
                          & ~((1u << lo) - 1u);
        atomicOr(&row[w], bits);
    }
}

// Kernel 2a: fused copy+mask via bitmask. One block per (row, 1024-sample chunk).
__global__ void pl_apply(const float* __restrict__ audio,
                         const unsigned int* __restrict__ mask,
                         float* __restrict__ out) {
    const int b   = blockIdx.y;
    const int tid = threadIdx.x;
    const int c0  = blockIdx.x * CHUNK;
    __shared__ unsigned int lm[32];

    if (tid < 32) {
        int w = (c0 >> 5) + tid;
        lm[tid] = (w < WPR) ? mask[(size_t)b * WPR + w] : 0u;
    }
    __syncthreads();

    const int s = c0 + tid * 4;
    if (s >= TLEN) return;

    unsigned int m4 = (lm[tid >> 3] >> ((tid & 7) * 4)) & 0xFu;

    const size_t idx = (size_t)b * TLEN + s;
    float4 v;
    if (m4 == 0xFu) {
        v = make_float4(0.f, 0.f, 0.f, 0.f);   // fully covered: skip fetch
    } else {
        v = *(const float4*)(audio + idx);
        if (m4 & 1u) v.x = 0.f;
        if (m4 & 2u) v.y = 0.f;
        if (m4 & 4u) v.z = 0.f;
        if (m4 & 8u) v.w = 0.f;
    }
    *(float4*)(out + idx) = v;
}

// Fallback path (small ws): plain copy + per-segment zero.
__global__ void pl_copy(const float4* __restrict__ in, float4* __restrict__ out, int n4) {
    int i = blockIdx.x * blockDim.x + threadIdx.x;
    int stride = gridDim.x * blockDim.x;
    for (; i < n4; i += stride) out[i] = in[i];
}

__global__ void pl_zero(const int* __restrict__ seg_start,
                        const int* __restrict__ seg_end,
                        float* __restrict__ out) {
    int idx = blockIdx.x;
    int b = idx / NSEG;
    int s0 = seg_start[idx];
    int s1 = seg_end[idx];
    float* row = out + (size_t)b * TLEN;
    for (int i = s0 + (int)threadIdx.x; i < s1; i += (int)blockDim.x)
        row[i] = 0.0f;
}

extern "C" void kernel_launch(void* const* d_in, const int* in_sizes, int n_in,
                              void* d_out, int out_size, void* d_ws, size_t ws_size,
                              hipStream_t stream) {
    const float* audio       = (const float*)d_in[0];
    const float* ratio       = (const float*)d_in[1];
    const int*   seg_len_raw = (const int*)d_in[2];
    const float* start_u     = (const float*)d_in[3];
    float* out = (float*)d_out;

    int* seg_start = (int*)d_ws;                    // BATCH*NSEG ints
    int* seg_end   = seg_start + BATCH * NSEG;      // BATCH*NSEG ints
    unsigned int* mask = (unsigned int*)(seg_end + BATCH * NSEG);

    const size_t need = (size_t)(2 * BATCH * NSEG) * 4 + (size_t)BATCH * WPR * 4;
    const bool use_mask = ws_size >= need;

    pl_segments<<<BATCH, 256, 0, stream>>>(ratio, seg_len_raw, start_u,
                                           seg_start, seg_end,
                                           use_mask ? mask : (unsigned int*)nullptr);

    if (use_mask) {
        pl_paint<<<BATCH * NSEG, 64, 0, stream>>>(seg_start, seg_end, mask);
        dim3 grid(NCHUNK, BATCH);
        pl_apply<<<grid, 256, 0, stream>>>(audio, mask, out);
    } else {
        const int n4 = BATCH * TLEN / 4;
        pl_copy<<<2048, 256, 0, stream>>>((const float4*)audio, (float4*)out, n4);
        pl_zero<<<BATCH * NSEG, 256, 0, stream>>>(seg_start, seg_end, out);
    }
}

// Round 5
// 32.358 us; speedup vs baseline: 1.5764x; 1.1661x over previous
//
#include <hip/hip_runtime.h>

#define BATCH 128
#define TLEN  160000
#define NSEG  200
#define CHUNK 1024
#define NCHUNK ((TLEN + CHUNK - 1) / CHUNK)   // 157
#define WPR   ((TLEN + 31) / 32)              // 5000 mask words per row

// Kernel 0 (fused): one block per row.
//  (a) LDS scan of 200 segment lengths -> exclusive prefix
//  (b) per-thread eff/start/end (exact reference float math)
//  (c) zero a 5000-word LDS bitmask, per-thread atomicOr-paint own segment
//  (d) coalesced LDS -> global mask write
__global__ void pl_segments_paint(const float* __restrict__ ratio,
                                  const int* __restrict__ seg_len_raw,
                                  const float* __restrict__ start_u,
                                  unsigned int* __restrict__ mask) {
    const int b   = blockIdx.x;
    const int tid = threadIdx.x;
    __shared__ int sc[256];
    __shared__ unsigned int lmask[WPR];

    // zero LDS mask
    for (int w = tid; w < WPR; w += 256) lmask[w] = 0u;

    const int base = b * NSEG;
    int len = (tid < NSEG) ? seg_len_raw[base + tid] : 0;

    // inclusive scan of lengths
    sc[tid] = len;
    __syncthreads();
    #pragma unroll
    for (int off = 1; off < 256; off <<= 1) {
        int t = (tid >= off) ? sc[tid - off] : 0;
        __syncthreads();
        sc[tid] += t;
        __syncthreads();
    }

    // per-segment interval + LDS paint
    if (tid < NSEG) {
        int total = (int)floorf((float)TLEN * ratio[b]);    // matches reference
        int prev  = sc[tid] - len;                          // exclusive prefix
        int rem   = total - prev;
        int eff   = rem < 0 ? 0 : (rem > len ? len : rem);  // clip(total-prev,0,len)
        float u   = start_u[base + tid];
        int s0    = (int)floorf(u * (float)(TLEN - eff + 1));
        int s1    = s0 + eff;
        if (s0 < s1) {
            int w0 = s0 >> 5;
            int w1 = (s1 - 1) >> 5;                         // inclusive
            for (int w = w0; w <= w1; ++w) {
                int lo = s0 - (w << 5); if (lo < 0) lo = 0;
                int hi = s1 - (w << 5); if (hi > 32) hi = 32;
                unsigned int bits = (hi == 32 ? 0xFFFFFFFFu : ((1u << hi) - 1u))
                                  & ~((1u << lo) - 1u);
                atomicOr(&lmask[w], bits);
            }
        }
    }
    __syncthreads();

    // coalesced mask writeback
    unsigned int* row = mask + (size_t)b * WPR;
    for (int w = tid; w < WPR; w += 256) row[w] = lmask[w];
}

// Kernel 1: fused copy+mask via bitmask. One block per (row, 1024-sample chunk).
__global__ void pl_apply(const float* __restrict__ audio,
                         const unsigned int* __restrict__ mask,
                         float* __restrict__ out) {
    const int b   = blockIdx.y;
    const int tid = threadIdx.x;
    const int c0  = blockIdx.x * CHUNK;
    __shared__ unsigned int lm[32];

    if (tid < 32) {
        int w = (c0 >> 5) + tid;
        lm[tid] = (w < WPR) ? mask[(size_t)b * WPR + w] : 0u;
    }
    __syncthreads();

    const int s = c0 + tid * 4;
    if (s >= TLEN) return;

    unsigned int m4 = (lm[tid >> 3] >> ((tid & 7) * 4)) & 0xFu;

    const size_t idx = (size_t)b * TLEN + s;
    float4 v;
    if (m4 == 0xFu) {
        v = make_float4(0.f, 0.f, 0.f, 0.f);   // fully covered: skip fetch
    } else {
        v = *(const float4*)(audio + idx);
        if (m4 & 1u) v.x = 0.f;
        if (m4 & 2u) v.y = 0.f;
        if (m4 & 4u) v.z = 0.f;
        if (m4 & 8u) v.w = 0.f;
    }
    *(float4*)(out + idx) = v;
}

extern "C" void kernel_launch(void* const* d_in, const int* in_sizes, int n_in,
                              void* d_out, int out_size, void* d_ws, size_t ws_size,
                              hipStream_t stream) {
    const float* audio       = (const float*)d_in[0];
    const float* ratio       = (const float*)d_in[1];
    const int*   seg_len_raw = (const int*)d_in[2];
    const float* start_u     = (const float*)d_in[3];
    float* out = (float*)d_out;

    unsigned int* mask = (unsigned int*)d_ws;    // [BATCH][WPR]

    pl_segments_paint<<<BATCH, 256, 0, stream>>>(ratio, seg_len_raw, start_u, mask);

    dim3 grid(NCHUNK, BATCH);
    pl_apply<<<grid, 256, 0, stream>>>(audio, mask, out);
}

// Round 6
// 32.296 us; speedup vs baseline: 1.5794x; 1.0019x over previous
//
#include <hip/hip_runtime.h>

#define BATCH 128
#define TLEN  160000
#define NSEG  200
#define CHUNK 8192
#define NCHUNK ((TLEN + CHUNK - 1) / CHUNK)   // 20
#define WPC   (CHUNK / 32)                    // 256 mask words per chunk
#define WPR   ((TLEN + 31) / 32)              // 5000 mask words per row

// Kernel 0 (fused): one block per row.
//  (a) LDS scan of 200 segment lengths -> exclusive prefix
//  (b) per-thread eff/start/end (exact reference float math)
//  (c) zero a 5000-word LDS bitmask, per-thread atomicOr-paint own segment
//  (d) coalesced LDS -> global mask write
__global__ void pl_segments_paint(const float* __restrict__ ratio,
                                  const int* __restrict__ seg_len_raw,
                                  const float* __restrict__ start_u,
                                  unsigned int* __restrict__ mask) {
    const int b   = blockIdx.x;
    const int tid = threadIdx.x;
    __shared__ int sc[256];
    __shared__ unsigned int lmask[WPR];

    // zero LDS mask
    for (int w = tid; w < WPR; w += 256) lmask[w] = 0u;

    const int base = b * NSEG;
    int len = (tid < NSEG) ? seg_len_raw[base + tid] : 0;

    // inclusive scan of lengths
    sc[tid] = len;
    __syncthreads();
    #pragma unroll
    for (int off = 1; off < 256; off <<= 1) {
        int t = (tid >= off) ? sc[tid - off] : 0;
        __syncthreads();
        sc[tid] += t;
        __syncthreads();
    }

    // per-segment interval + LDS paint
    if (tid < NSEG) {
        int total = (int)floorf((float)TLEN * ratio[b]);    // matches reference
        int prev  = sc[tid] - len;                          // exclusive prefix
        int rem   = total - prev;
        int eff   = rem < 0 ? 0 : (rem > len ? len : rem);  // clip(total-prev,0,len)
        float u   = start_u[base + tid];
        int s0    = (int)floorf(u * (float)(TLEN - eff + 1));
        int s1    = s0 + eff;
        if (s0 < s1) {
            int w0 = s0 >> 5;
            int w1 = (s1 - 1) >> 5;                         // inclusive
            for (int w = w0; w <= w1; ++w) {
                int lo = s0 - (w << 5); if (lo < 0) lo = 0;
                int hi = s1 - (w << 5); if (hi > 32) hi = 32;
                unsigned int bits = (hi == 32 ? 0xFFFFFFFFu : ((1u << hi) - 1u))
                                  & ~((1u << lo) - 1u);
                atomicOr(&lmask[w], bits);
            }
        }
    }
    __syncthreads();

    // coalesced mask writeback
    unsigned int* row = mask + (size_t)b * WPR;
    for (int w = tid; w < WPR; w += 256) row[w] = lmask[w];
}

// Kernel 1: fused copy+mask via bitmask. One block per (row, 8192-sample chunk).
// Every thread loads one mask word (coalesced), then processes 8 float4s.
__global__ void pl_apply(const float* __restrict__ audio,
                         const unsigned int* __restrict__ mask,
                         float* __restrict__ out) {
    const int b   = blockIdx.y;
    const int tid = threadIdx.x;
    const int c0  = blockIdx.x * CHUNK;
    __shared__ unsigned int lm[WPC];

    {
        int w = (c0 >> 5) + tid;
        lm[tid] = (w < WPR) ? mask[(size_t)b * WPR + w] : 0u;
    }
    __syncthreads();

    const size_t rowbase = (size_t)b * TLEN;

    #pragma unroll
    for (int i = 0; i < CHUNK / 1024; ++i) {
        const int e = i * 256 + tid;       // float4 index within chunk
        const int s = c0 + e * 4;
        if (s >= TLEN) break;

        unsigned int m4 = (lm[e >> 3] >> ((e & 7) * 4)) & 0xFu;

        const size_t idx = rowbase + s;
        float4 v;
        if (m4 == 0xFu) {
            v = make_float4(0.f, 0.f, 0.f, 0.f);   // fully covered: skip fetch
        } else {
            v = *(const float4*)(audio + idx);
            if (m4 & 1u) v.x = 0.f;
            if (m4 & 2u) v.y = 0.f;
            if (m4 & 4u) v.z = 0.f;
            if (m4 & 8u) v.w = 0.f;
        }
        *(float4*)(out + idx) = v;
    }
}

extern "C" void kernel_launch(void* const* d_in, const int* in_sizes, int n_in,
                              void* d_out, int out_size, void* d_ws, size_t ws_size,
                              hipStream_t stream) {
    const float* audio       = (const float*)d_in[0];
    const float* ratio       = (const float*)d_in[1];
    const int*   seg_len_raw = (const int*)d_in[2];
    const float* start_u     = (const float*)d_in[3];
    float* out = (float*)d_out;

    unsigned int* mask = (unsigned int*)d_ws;    // [BATCH][WPR]

    pl_segments_paint<<<BATCH, 256, 0, stream>>>(ratio, seg_len_raw, start_u, mask);

    dim3 grid(NCHUNK, BATCH);
    pl_apply<<<grid, 256, 0, stream>>>(audio, mask, out);
}

// Round 7
// 28.660 us; speedup vs baseline: 1.7798x; 1.1268x over previous
//
#include <hip/hip_runtime.h>

#define BATCH 128
#define TLEN  160000
#define NSEG  200
#define CHUNK 8192
#define NCHUNK ((TLEN + CHUNK - 1) / CHUNK)   // 20
#define WPC   (CHUNK / 32)                    // 256 mask words per chunk

// Single fused kernel. One block per (row, 8192-sample chunk).
//  (a) coalesced load of the row's 200 segment lengths, LDS scan
//  (b) per-thread eff/start/end (exact reference float math)
//  (c) intersect each segment with this block's window; atomicOr-paint the
//      overlap into a 256-word LDS bitmask (max 51 words per segment)
//  (d) masked copy: fully-covered float4s skip the audio fetch
__global__ void pl_fused(const float* __restrict__ audio,
                         const float* __restrict__ ratio,
                         const int* __restrict__ seg_len_raw,
                         const float* __restrict__ start_u,
                         float* __restrict__ out) {
    const int b   = blockIdx.y;
    const int tid = threadIdx.x;
    const int c0  = blockIdx.x * CHUNK;
    const int c1  = (c0 + CHUNK < TLEN) ? c0 + CHUNK : TLEN;

    __shared__ int sc[256];
    __shared__ unsigned int lm[WPC];

    lm[tid] = 0u;

    const int base = b * NSEG;
    int len = (tid < NSEG) ? seg_len_raw[base + tid] : 0;

    // inclusive scan of lengths (entries >= NSEG are 0)
    sc[tid] = len;
    __syncthreads();
    #pragma unroll
    for (int off = 1; off < 256; off <<= 1) {
        int t = (tid >= off) ? sc[tid - off] : 0;
        __syncthreads();
        sc[tid] += t;
        __syncthreads();
    }

    // per-segment interval, clipped to this window, painted into LDS
    if (tid < NSEG) {
        int total = (int)floorf((float)TLEN * ratio[b]);    // matches reference
        int prev  = sc[tid] - len;                          // exclusive prefix
        int rem   = total - prev;
        int eff   = rem < 0 ? 0 : (rem > len ? len : rem);  // clip(total-prev,0,len)
        float u   = start_u[base + tid];
        int s0    = (int)floorf(u * (float)(TLEN - eff + 1));
        int s1    = s0 + eff;
        int a = (s0 > c0) ? s0 : c0;
        int e = (s1 < c1) ? s1 : c1;
        if (a < e) {
            int w0 = (a - c0) >> 5;
            int w1 = (e - 1 - c0) >> 5;                     // inclusive
            for (int w = w0; w <= w1; ++w) {
                int lo = (a - c0) - (w << 5); if (lo < 0) lo = 0;
                int hi = (e - c0) - (w << 5); if (hi > 32) hi = 32;
                unsigned int bits = (hi == 32 ? 0xFFFFFFFFu : ((1u << hi) - 1u))
                                  & ~((1u << lo) - 1u);
                atomicOr(&lm[w], bits);
            }
        }
    }
    __syncthreads();

    // masked copy: 8 float4s per thread
    const size_t rowbase = (size_t)b * TLEN;
    #pragma unroll
    for (int i = 0; i < CHUNK / 1024; ++i) {
        const int e4 = i * 256 + tid;          // float4 index within chunk
        const int s  = c0 + e4 * 4;
        if (s >= TLEN) break;

        unsigned int m4 = (lm[e4 >> 3] >> ((e4 & 7) * 4)) & 0xFu;

        const size_t idx = rowbase + s;
        float4 v;
        if (m4 == 0xFu) {
            v = make_float4(0.f, 0.f, 0.f, 0.f);   // fully covered: skip fetch
        } else {
            v = *(const float4*)(audio + idx);
            if (m4 & 1u) v.x = 0.f;
            if (m4 & 2u) v.y = 0.f;
            if (m4 & 4u) v.z = 0.f;
            if (m4 & 8u) v.w = 0.f;
        }
        *(float4*)(out + idx) = v;
    }
}

extern "C" void kernel_launch(void* const* d_in, const int* in_sizes, int n_in,
                              void* d_out, int out_size, void* d_ws, size_t ws_size,
                              hipStream_t stream) {
    const float* audio       = (const float*)d_in[0];
    const float* ratio       = (const float*)d_in[1];
    const int*   seg_len_raw = (const int*)d_in[2];
    const float* start_u     = (const float*)d_in[3];
    float* out = (float*)d_out;

    dim3 grid(NCHUNK, BATCH);
    pl_fused<<<grid, 256, 0, stream>>>(audio, ratio, seg_len_raw, start_u, out);
}

// Round 8
// 27.766 us; speedup vs baseline: 1.8371x; 1.0322x over previous
//
#include <hip/hip_runtime.h>

#define BATCH 128
#define TLEN  160000
#define NSEG  200
#define CHUNK 16384
#define NCHUNK ((TLEN + CHUNK - 1) / CHUNK)   // 10
#define WPC   (CHUNK / 32)                    // 512 mask words per chunk

// Single fused kernel. One block per (row, 16384-sample chunk).
//  (a) wave64 shuffle inclusive scan of the row's 200 segment lengths
//      (6 shfl steps, 1 barrier for cross-wave combine — no LDS scan array)
//  (b) per-thread eff/start/end (exact reference float math)
//  (c) intersect each segment with this block's window; atomicOr-paint the
//      overlap into a 512-word LDS bitmask
//  (d) masked copy: fully-covered float4s skip the audio fetch
__global__ void pl_fused(const float* __restrict__ audio,
                         const float* __restrict__ ratio,
                         const int* __restrict__ seg_len_raw,
                         const float* __restrict__ start_u,
                         float* __restrict__ out) {
    const int b    = blockIdx.y;
    const int tid  = threadIdx.x;
    const int wave = tid >> 6;
    const int lane = tid & 63;
    const int c0   = blockIdx.x * CHUNK;
    const int c1   = (c0 + CHUNK < TLEN) ? c0 + CHUNK : TLEN;

    __shared__ unsigned int lm[WPC];
    __shared__ int wsum[4];

    // zero LDS mask (covered by the scan barrier below)
    lm[tid]       = 0u;
    lm[tid + 256] = 0u;

    const int base = b * NSEG;
    const int len  = (tid < NSEG) ? seg_len_raw[base + tid] : 0;

    // in-register inclusive scan within each wave (64 lanes)
    int incl = len;
    #pragma unroll
    for (int off = 1; off < 64; off <<= 1) {
        int t = __shfl_up(incl, off, 64);
        if (lane >= off) incl += t;
    }
    if (lane == 63) wsum[wave] = incl;
    __syncthreads();

    // add totals of preceding waves -> full inclusive scan over 256
    int woff = 0;
    #pragma unroll
    for (int w = 0; w < 4; ++w)
        if (w < wave) woff += wsum[w];
    incl += woff;

    // per-segment interval, clipped to this window, painted into LDS
    if (tid < NSEG) {
        int total = (int)floorf((float)TLEN * ratio[b]);    // matches reference
        int prev  = incl - len;                             // exclusive prefix
        int rem   = total - prev;
        int eff   = rem < 0 ? 0 : (rem > len ? len : rem);  // clip(total-prev,0,len)
        float u   = start_u[base + tid];
        int s0    = (int)floorf(u * (float)(TLEN - eff + 1));
        int s1    = s0 + eff;
        int a = (s0 > c0) ? s0 : c0;
        int e = (s1 < c1) ? s1 : c1;
        if (a < e) {
            int w0 = (a - c0) >> 5;
            int w1 = (e - 1 - c0) >> 5;                     // inclusive
            for (int w = w0; w <= w1; ++w) {
                int lo = (a - c0) - (w << 5); if (lo < 0) lo = 0;
                int hi = (e - c0) - (w << 5); if (hi > 32) hi = 32;
                unsigned int bits = (hi == 32 ? 0xFFFFFFFFu : ((1u << hi) - 1u))
                                  & ~((1u << lo) - 1u);
                atomicOr(&lm[w], bits);
            }
        }
    }
    __syncthreads();

    // masked copy: 16 float4s per thread
    const size_t rowbase = (size_t)b * TLEN;
    #pragma unroll
    for (int i = 0; i < CHUNK / 1024; ++i) {
        const int e4 = i * 256 + tid;          // float4 index within chunk
        const int s  = c0 + e4 * 4;
        if (s >= TLEN) break;

        unsigned int m4 = (lm[e4 >> 3] >> ((e4 & 7) * 4)) & 0xFu;

        const size_t idx = rowbase + s;
        float4 v;
        if (m4 == 0xFu) {
            v = make_float4(0.f, 0.f, 0.f, 0.f);   // fully covered: skip fetch
        } else {
            v = *(const float4*)(audio + idx);
            if (m4 & 1u) v.x = 0.f;
            if (m4 & 2u) v.y = 0.f;
            if (m4 & 4u) v.z = 0.f;
            if (m4 & 8u) v.w = 0.f;
        }
        *(float4*)(out + idx) = v;
    }
}

extern "C" void kernel_launch(void* const* d_in, const int* in_sizes, int n_in,
                              void* d_out, int out_size, void* d_ws, size_t ws_size,
                              hipStream_t stream) {
    const float* audio       = (const float*)d_in[0];
    const float* ratio       = (const float*)d_in[1];
    const int*   seg_len_raw = (const int*)d_in[2];
    const float* start_u     = (const float*)d_in[3];
    float* out = (float*)d_out;

    dim3 grid(NCHUNK, BATCH);
    pl_fused<<<grid, 256, 0, stream>>>(audio, ratio, seg_len_raw, start_u, out);
}